// Round 1
// baseline (27642.557 us; speedup 1.0000x reference)
//
#include <hip/hip_runtime.h>
#include <hip/hip_bf16.h>
#include <stdint.h>
#include <math.h>

// Problem dims
constexpr int SEQ  = 4096;
constexpr int DIN  = 1152;
constexpr int HID  = 512;
constexpr int G4H  = 2048;   // 4*HID
constexpr int KTAG = 24;
constexpr float NEGV = -10000.0f;

__device__ __forceinline__ float sigm(float x) { return 1.0f / (1.0f + expf(-x)); }

// =====================================================================
// GEMM: C[SEQ][2048] = A[SEQ][KA] @ W[2048][KA]^T + b     (fp32, 64x64 tile)
// mode 0: A is a plain [SEQ][KA] matrix.
// mode 1: A row t is concat(hf[t+1][0:512], hb[SEQ-t][0:512])  (bidir LSTM output)
// blockIdx.z selects the (Wf,bf,Cf) or (Wb,bb,Cb) problem.
// =====================================================================
__global__ __launch_bounds__(256) void gemm_proj(
    const float* __restrict__ A, const float* __restrict__ hf, const float* __restrict__ hb,
    int KA, int mode,
    const float* __restrict__ Wf, const float* __restrict__ bf, float* __restrict__ Cf,
    const float* __restrict__ Wb, const float* __restrict__ bb, float* __restrict__ Cb)
{
    const float* W    = blockIdx.z ? Wb : Wf;
    const float* bias = blockIdx.z ? bb : bf;
    float*       C    = blockIdx.z ? Cb : Cf;

    __shared__ __align__(16) float As[32][68];   // [k][m], pad 68 to break conflicts, keep 16B align
    __shared__ __align__(16) float Ws[32][68];   // [k][n]

    const int tid  = threadIdx.x;
    const int bm   = blockIdx.x * 64;
    const int bn   = blockIdx.y * 64;
    const int lrow = tid >> 2;          // 0..63
    const int kq   = (tid & 3) * 8;     // 0,8,16,24
    const int tx   = tid & 15, ty = tid >> 4;

    float acc[4][4] = {};

    for (int bk = 0; bk < KA; bk += 32) {
        float4 a0, a1;
        const int arow = bm + lrow;
        const int k0   = bk + kq;
        if (mode == 0) {
            const float* p = A + (size_t)arow * KA + k0;
            a0 = *(const float4*)p;
            a1 = *(const float4*)(p + 4);
        } else {
            const float* p0 = (k0 < 512) ? (hf + (size_t)(arow + 1) * HID + k0)
                                         : (hb + (size_t)(SEQ - arow) * HID + (k0 - 512));
            const int k1 = k0 + 4;
            const float* p1 = (k1 < 512) ? (hf + (size_t)(arow + 1) * HID + k1)
                                         : (hb + (size_t)(SEQ - arow) * HID + (k1 - 512));
            a0 = *(const float4*)p0;
            a1 = *(const float4*)p1;
        }
        const float* q = W + (size_t)(bn + lrow) * KA + k0;
        const float4 w0 = *(const float4*)q;
        const float4 w1 = *(const float4*)(q + 4);

        As[kq+0][lrow] = a0.x; As[kq+1][lrow] = a0.y; As[kq+2][lrow] = a0.z; As[kq+3][lrow] = a0.w;
        As[kq+4][lrow] = a1.x; As[kq+5][lrow] = a1.y; As[kq+6][lrow] = a1.z; As[kq+7][lrow] = a1.w;
        Ws[kq+0][lrow] = w0.x; Ws[kq+1][lrow] = w0.y; Ws[kq+2][lrow] = w0.z; Ws[kq+3][lrow] = w0.w;
        Ws[kq+4][lrow] = w1.x; Ws[kq+5][lrow] = w1.y; Ws[kq+6][lrow] = w1.z; Ws[kq+7][lrow] = w1.w;
        __syncthreads();

        #pragma unroll
        for (int kk = 0; kk < 32; ++kk) {
            const float4 av = *(const float4*)&As[kk][ty * 4];
            const float4 wv = *(const float4*)&Ws[kk][tx * 4];
            acc[0][0] = fmaf(av.x, wv.x, acc[0][0]); acc[0][1] = fmaf(av.x, wv.y, acc[0][1]);
            acc[0][2] = fmaf(av.x, wv.z, acc[0][2]); acc[0][3] = fmaf(av.x, wv.w, acc[0][3]);
            acc[1][0] = fmaf(av.y, wv.x, acc[1][0]); acc[1][1] = fmaf(av.y, wv.y, acc[1][1]);
            acc[1][2] = fmaf(av.y, wv.z, acc[1][2]); acc[1][3] = fmaf(av.y, wv.w, acc[1][3]);
            acc[2][0] = fmaf(av.z, wv.x, acc[2][0]); acc[2][1] = fmaf(av.z, wv.y, acc[2][1]);
            acc[2][2] = fmaf(av.z, wv.z, acc[2][2]); acc[2][3] = fmaf(av.z, wv.w, acc[2][3]);
            acc[3][0] = fmaf(av.w, wv.x, acc[3][0]); acc[3][1] = fmaf(av.w, wv.y, acc[3][1]);
            acc[3][2] = fmaf(av.w, wv.z, acc[3][2]); acc[3][3] = fmaf(av.w, wv.w, acc[3][3]);
        }
        __syncthreads();
    }

    const float4 bv = *(const float4*)&bias[bn + tx * 4];
    #pragma unroll
    for (int im = 0; im < 4; ++im) {
        float4 o;
        o.x = acc[im][0] + bv.x; o.y = acc[im][1] + bv.y;
        o.z = acc[im][2] + bv.z; o.w = acc[im][3] + bv.w;
        *(float4*)&C[(size_t)(bm + ty * 4 + im) * G4H + bn + tx * 4] = o;
    }
}

// =====================================================================
// Persistent bidirectional LSTM layer, v2 (wave-independent gate path).
// 128 WGs x 256 threads. WGs [0,64): forward dir, [64,128): backward dir.
// Each WG owns 8 hidden units; each WAVE owns 2 units end-to-end:
//   lane = RR*8 + kc;  RR in [0,8) = (unit-in-wave up = RR>>2, gate g = RR&3),
//   kc in [0,8) = 64-float k-chunk.  The per-lane 64-fma dependent chain and
//   the combine order (((c0+c1)+(c2+c3))+(c4+c5))+(c6+c7) + zP reproduce the
//   previous kernel's fp32 arithmetic bit-exactly (absmax must stay 0.0).
// Changes vs v1 (both were on the per-step critical latency chain):
//   - zP (input-projection term) software-pipelined one step ahead: its
//     ~700-900cy LLC latency is fully hidden instead of stalling wave0.
//   - no part[] LDS cross-wave reduce, no wave0-only serialization: shuffles
//     only, and the h stores issue from all 4 waves ~250cy earlier.
//   - h staged in padded LDS (68 floats per 64-chunk, 16B-aligned) so the
//     per-row ds_read_b128 pattern is bank-conflict-free (linear layout
//     would be 8-way same-bank).
// h exchanged via hist[s] slots in global memory using NaN-sentinel value-
// spin (relaxed agent-scope atomics). hist must be pre-filled 0xFF.
// =====================================================================
__global__ __launch_bounds__(256) void lstm_layer(
    const float* __restrict__ Pf, const float* __restrict__ Pb,
    const float* __restrict__ Whhf, const float* __restrict__ Whhb,
    const float* __restrict__ h0, const float* __restrict__ c0, int h0base,
    float* __restrict__ histf, float* __restrict__ histb)
{
    const int wg  = blockIdx.x;
    const int dir = wg >> 6;            // 0 fwd, 1 bwd
    const int w   = wg & 63;            // slice id
    const float* P    = dir ? Pb : Pf;
    const float* Whh  = dir ? Whhb : Whhf;
    float* histW      = dir ? histb : histf;

    const int tid  = threadIdx.x;
    const int wave = tid >> 6;                 // 0..3
    const int lane = tid & 63;
    const int RR   = lane >> 3;                // 0..7: row within wave
    const int kc   = lane & 7;                 // 0..7: 64-float k-chunk
    const int up   = RR >> 2;                  // unit-in-wave 0/1
    const int g    = RR & 3;                   // gate i,f,g,o
    const int unit = (w << 3) + (wave << 1) + up;   // hidden index [0,512)
    const int grow = g * HID + unit;           // z row in [0,2048)

    // weights -> registers (64 floats)
    float4 wv[16];
    {
        const float4* wp = (const float4*)(Whh + (size_t)grow * HID + kc * 64);
        #pragma unroll
        for (int i = 0; i < 16; ++i) wv[i] = wp[i];
    }

    // c replicated across each 32-lane half (all lanes compute identical cell
    // math from shuffled gates; only lanes 0/32 store).
    float c = c0[(size_t)(h0base + dir) * HID + unit];

    // padded h: chunk kc lives at [kc*68, kc*68+64); 68*4B=272B = 17*16B keeps
    // float4 alignment, and kc*68 % 32 = kc*4 spreads chunks across banks.
    __shared__ __align__(16) float hsp[8 * 68];

    // initial h into padded LDS
    {
        const int e = tid * 2;                 // 0..510
        const float2 h2 = *(const float2*)&h0[(size_t)(h0base + dir) * HID + e];
        *(float2*)&hsp[(e >> 6) * 68 + (e & 63)] = h2;
    }
    __syncthreads();

    // zP for step 0 (pipelined register thereafter)
    float zPc = P[(size_t)(dir ? (SEQ - 1) : 0) * G4H + grow];

    for (int s = 0; s < SEQ; ++s) {
        // prefetch next step's input-projection term (used ~1 full step later;
        // its LLC latency is entirely off the critical path)
        float zPn = 0.0f;
        if (s + 1 < SEQ) {
            const int tn = dir ? (SEQ - 2 - s) : (s + 1);
            zPn = P[(size_t)tn * G4H + grow];
        }

        // matvec partial: this lane's 64-fma dependent chain (same order as v1)
        float acc = 0.0f;
        const float* hb4 = &hsp[kc * 68];
        #pragma unroll
        for (int i = 0; i < 16; ++i) {
            const float4 h4 = *(const float4*)&hb4[i * 4];
            acc = fmaf(wv[i].x, h4.x, acc);
            acc = fmaf(wv[i].y, h4.y, acc);
            acc = fmaf(wv[i].z, h4.z, acc);
            acc = fmaf(wv[i].w, h4.w, acc);
        }
        __syncthreads();   // all waves done READING hsp; spin below may refill it

        // pair sums p_i = c_{2i}+c_{2i+1} (commutative, bit-exact on odd lanes)
        const float s2 = acc + __shfl_xor(acc, 1);
        // z = (((p0+p1)+p2)+p3) + zP  — exact v1 association
        const int base = RR << 3;
        float z = __shfl(s2, base) + __shfl(s2, base + 2);
        z += __shfl(s2, base + 4);
        z += __shfl(s2, base + 6);
        z += zPc;

        // gate gather for this half-wave's unit; identical cell math as v1
        const int hb32 = lane & 32;
        const float zi = __shfl(z, hb32 + 0);
        const float zf = __shfl(z, hb32 + 8);
        const float zg = __shfl(z, hb32 + 16);
        const float zo = __shfl(z, hb32 + 24);
        const float cn = sigm(zf) * c + sigm(zi) * tanhf(zg);
        const float hv = sigm(zo) * tanhf(cn);
        c = cn;
        if ((lane & 31) == 0) {
            __hip_atomic_store(&histW[(size_t)(s + 1) * HID + unit], hv,
                               __ATOMIC_RELAXED, __HIP_MEMORY_SCOPE_AGENT);
        }
        zPc = zPn;

        if (s + 1 < SEQ) {
            const uint64_t* src = (const uint64_t*)(histW + (size_t)(s + 1) * HID);
            uint64_t v;
            do {
                v = __hip_atomic_load(&src[tid], __ATOMIC_RELAXED, __HIP_MEMORY_SCOPE_AGENT);
            } while ((uint32_t)v == 0xFFFFFFFFu || (uint32_t)(v >> 32) == 0xFFFFFFFFu);
            const int e = tid * 2;
            float2 h2;
            h2.x = __uint_as_float((uint32_t)v);
            h2.y = __uint_as_float((uint32_t)(v >> 32));
            *(float2*)&hsp[(e >> 6) * 68 + (e & 63)] = h2;
            __syncthreads();
        }
    }
}

// =====================================================================
// feats[t][j] = b_tag[j] + sum_k y1[t][k] * Wtag[j][k], y1 from hist buffers.
// One wave per t-row.
// =====================================================================
__global__ __launch_bounds__(256) void feats_kernel(
    const float* __restrict__ hf, const float* __restrict__ hb,
    const float* __restrict__ Wtag, const float* __restrict__ btag, float* __restrict__ feats)
{
    const int wv = threadIdx.x >> 6, lane = threadIdx.x & 63;
    const int t  = blockIdx.x * 4 + wv;
    const int k0 = lane * 16;
    const float* src = (k0 < 512) ? (hf + (size_t)(t + 1) * HID + k0)
                                  : (hb + (size_t)(SEQ - t) * HID + (k0 - 512));
    const float4 y0 = ((const float4*)src)[0];
    const float4 y1 = ((const float4*)src)[1];
    const float4 y2 = ((const float4*)src)[2];
    const float4 y3 = ((const float4*)src)[3];
    for (int j = 0; j < KTAG; ++j) {
        const float4* wp = (const float4*)&Wtag[(size_t)j * 1024 + k0];
        const float4 w0 = wp[0], w1 = wp[1], w2 = wp[2], w3 = wp[3];
        float p = 0.0f;
        p = fmaf(y0.x, w0.x, p); p = fmaf(y0.y, w0.y, p); p = fmaf(y0.z, w0.z, p); p = fmaf(y0.w, w0.w, p);
        p = fmaf(y1.x, w1.x, p); p = fmaf(y1.y, w1.y, p); p = fmaf(y1.z, w1.z, p); p = fmaf(y1.w, w1.w, p);
        p = fmaf(y2.x, w2.x, p); p = fmaf(y2.y, w2.y, p); p = fmaf(y2.z, w2.z, p); p = fmaf(y2.w, w2.w, p);
        p = fmaf(y3.x, w3.x, p); p = fmaf(y3.y, w3.y, p); p = fmaf(y3.z, w3.z, p); p = fmaf(y3.w, w3.w, p);
        #pragma unroll
        for (int off = 32; off; off >>= 1) p += __shfl_xor(p, off);
        if (lane == 0) feats[(size_t)t * KTAG + j] = p + btag[j];
    }
}

// =====================================================================
// Sequential Viterbi max scan (bit-exact vs reference, no argmax on chain).
// 1 wave. Lane layout: to = lane%24, half = lane/24 covers 12 'from' each.
// fv rows stored to fvstore (slot 0 = init, slot t+1 = fv_t) for bp recompute.
// =====================================================================
__global__ __launch_bounds__(64) void viterbi_scan(
    const float* __restrict__ feats, const float* __restrict__ trans,
    float* __restrict__ fvstore, float* __restrict__ out, int* __restrict__ bestb)
{
    const int lane = threadIdx.x;
    const int to = lane % 24, hh = lane / 24;
    const bool act = hh < 2;
    const int hb = (hh & 1) * 12;

    float tr[12], fvr[12];
    #pragma unroll
    for (int i = 0; i < 12; ++i) tr[i] = act ? trans[to * 24 + hb + i] : -3.0e37f;
    #pragma unroll
    for (int i = 0; i < 12; ++i) fvr[i] = (hb + i == 0) ? 0.0f : NEGV;
    if (lane < 24) fvstore[lane] = (lane == 0) ? 0.0f : NEGV;

    float ftc = (lane < 24) ? feats[lane] : 0.0f;
    const int partner = act ? (to + ((hh ^ 1) * 24)) : lane;
    float fvnew = 0.0f;

    for (int t = 0; t < SEQ; ++t) {
        const float ftn = (lane < 24 && t + 1 < SEQ) ? feats[(size_t)(t + 1) * KTAG + lane] : 0.0f;
        float v0  = fvr[0]  + tr[0],  v1  = fvr[1]  + tr[1];
        float v2  = fvr[2]  + tr[2],  v3  = fvr[3]  + tr[3];
        float v4  = fvr[4]  + tr[4],  v5  = fvr[5]  + tr[5];
        float v6  = fvr[6]  + tr[6],  v7  = fvr[7]  + tr[7];
        float v8  = fvr[8]  + tr[8],  v9  = fvr[9]  + tr[9];
        float v10 = fvr[10] + tr[10], v11 = fvr[11] + tr[11];
        float m = fmaxf(fmaxf(fmaxf(v0, v1), fmaxf(v2, v3)),
                        fmaxf(fmaxf(v4, v5), fmaxf(v6, v7)));
        m = fmaxf(m, fmaxf(fmaxf(v8, v9), fmaxf(v10, v11)));
        m = fmaxf(m, __shfl(m, partner));
        fvnew = m + ftc;                 // valid on lanes < 24
        if (lane < 24) fvstore[(size_t)(t + 1) * KTAG + lane] = fvnew;
        #pragma unroll
        for (int i = 0; i < 12; ++i) fvr[i] = __shfl(fvnew, hb + i);   // re-replicate
        ftc = ftn;
    }

    // terminal
    float val = -3.0e38f; int idx = lane;
    if (lane < 24) {
        val = fvnew + trans[1 * 24 + lane];          // transitions[STOP][from]
        if (lane == 0 || lane == 1) val = NEGV;      // exclude START, STOP
    }
    #pragma unroll
    for (int off = 16; off; off >>= 1) {
        const float ov = __shfl_xor(val, off);
        const int   oi = __shfl_xor(idx, off);
        if (ov > val || (ov == val && oi < idx)) { val = ov; idx = oi; }
    }
    if (lane == 0) { out[0] = val; *bestb = idx; }
}

// =====================================================================
// Recompute backpointers in parallel: bp[t][to] = argmax_from(fv_{t-1}[from]+trans)
// Identical fp32 adds + first-index tie rule -> matches the sequential scan.
// =====================================================================
__global__ __launch_bounds__(256) void bp_kernel(
    const float* __restrict__ fvstore, const float* __restrict__ trans, uint8_t* __restrict__ bp)
{
    const int idx = blockIdx.x * 256 + threadIdx.x;
    const int t = idx / KTAG, to = idx % KTAG;
    const float* fv = fvstore + (size_t)t * KTAG;   // slot t = fv_{t-1}
    const float* tr = trans + to * 24;
    float m = fv[0] + tr[0]; int bi = 0;
    #pragma unroll
    for (int f = 1; f < 24; ++f) {
        const float v = fv[f] + tr[f];
        if (v > m) { m = v; bi = f; }
    }
    bp[idx] = (uint8_t)bi;
}

// =====================================================================
// Parallel backtrace via exact integer map composition over 64-step chunks.
// =====================================================================
__global__ __launch_bounds__(1024) void backtrace_kernel(
    const uint8_t* __restrict__ bp, const int* __restrict__ bestb, float* __restrict__ out)
{
    __shared__ uint8_t E[64][24];
    __shared__ uint8_t tops[64];
    const int tid = threadIdx.x;
    const int wv = tid >> 6, lane = tid & 63;

    // phase 1: chunk maps E_c: top_c -> top_{c-1} (applies bp[64c+63] .. bp[64c])
    for (int ci = 0; ci < 4; ++ci) {
        const int ck = wv * 4 + ci;
        if (lane < 24) {
            int y = lane;
            for (int k = 63; k >= 0; --k) y = bp[(size_t)(ck * 64 + k) * KTAG + y];
            E[ck][lane] = (uint8_t)y;
        }
    }
    __syncthreads();

    // phase 2: serial fold over 64 chunk maps
    if (tid == 0) {
        int topc = *bestb;
        tops[63] = (uint8_t)topc;
        for (int ck = 63; ck >= 1; --ck) { topc = E[ck][topc]; tops[ck - 1] = (uint8_t)topc; }
    }
    __syncthreads();

    // phase 3: fill each chunk
    for (int ci = 0; ci < 4; ++ci) {
        const int ck = wv * 4 + ci;
        if (lane == 0) {
            int y = tops[ck];
            out[1 + ck * 64 + 63] = (float)y;
            for (int tt = ck * 64 + 62; tt >= ck * 64; --tt) {
                y = bp[(size_t)(tt + 1) * KTAG + y];
                out[1 + tt] = (float)y;
            }
        }
    }
}

// =====================================================================
extern "C" void kernel_launch(void* const* d_in, const int* in_sizes, int n_in,
                              void* d_out, int out_size, void* d_ws, size_t ws_size,
                              hipStream_t stream)
{
    (void)in_sizes; (void)n_in; (void)out_size; (void)ws_size;
    // Inputs in setup_inputs() dict INSERTION order: transitions is added
    // LAST (after h0/c0), even though the reference signature lists it earlier.
    const float* X     = (const float*)d_in[0];
    const float* Wih0f = (const float*)d_in[1];
    const float* Whh0f = (const float*)d_in[2];
    const float* b0f   = (const float*)d_in[3];
    const float* Wih0b = (const float*)d_in[4];
    const float* Whh0b = (const float*)d_in[5];
    const float* b0b   = (const float*)d_in[6];
    const float* Wih1f = (const float*)d_in[7];
    const float* Whh1f = (const float*)d_in[8];
    const float* b1f   = (const float*)d_in[9];
    const float* Wih1b = (const float*)d_in[10];
    const float* Whh1b = (const float*)d_in[11];
    const float* b1b   = (const float*)d_in[12];
    const float* Wtag  = (const float*)d_in[13];
    const float* btag  = (const float*)d_in[14];
    const float* h0    = (const float*)d_in[15];
    const float* c0    = (const float*)d_in[16];
    const float* trans = (const float*)d_in[17];
    float* out = (float*)d_out;

    // workspace carve-up (floats)
    float* f   = (float*)d_ws;
    float* Pf  = f;                                   // SEQ*2048
    float* Pb  = Pf  + (size_t)SEQ * G4H;             // SEQ*2048
    float* hf0 = Pb  + (size_t)SEQ * G4H;             // (SEQ+1)*512 each
    float* hb0 = hf0 + (size_t)(SEQ + 1) * HID;
    float* hf1 = hb0 + (size_t)(SEQ + 1) * HID;
    float* hb1 = hf1 + (size_t)(SEQ + 1) * HID;
    float* feats = hb1 + (size_t)(SEQ + 1) * HID;     // SEQ*24
    float* fvst  = feats + (size_t)SEQ * KTAG;        // (SEQ+1)*24
    int*   bestb = (int*)(fvst + (size_t)(SEQ + 1) * KTAG);
    uint8_t* bp  = (uint8_t*)(bestb + 4);             // SEQ*24 bytes

    // NaN-sentinel fill for all 4 hist buffers (sync mechanism for the LSTM)
    hipMemsetAsync(hf0, 0xFF, (size_t)4 * (SEQ + 1) * HID * sizeof(float), stream);

    // layer 0: input projection, then persistent bidirectional recurrence
    gemm_proj<<<dim3(SEQ / 64, G4H / 64, 2), 256, 0, stream>>>(
        X, nullptr, nullptr, DIN, 0, Wih0f, b0f, Pf, Wih0b, b0b, Pb);
    lstm_layer<<<128, 256, 0, stream>>>(Pf, Pb, Whh0f, Whh0b, h0, c0, 0, hf0, hb0);

    // layer 1 (P buffers reused; layer-0 input y0 read straight from hist)
    gemm_proj<<<dim3(SEQ / 64, G4H / 64, 2), 256, 0, stream>>>(
        nullptr, hf0, hb0, 1024, 1, Wih1f, b1f, Pf, Wih1b, b1b, Pb);
    lstm_layer<<<128, 256, 0, stream>>>(Pf, Pb, Whh1f, Whh1b, h0, c0, 2, hf1, hb1);

    // tag head + Viterbi
    feats_kernel<<<SEQ / 4, 256, 0, stream>>>(hf1, hb1, Wtag, btag, feats);
    viterbi_scan<<<1, 64, 0, stream>>>(feats, trans, fvst, out, bestb);
    bp_kernel<<<(SEQ * KTAG) / 256, 256, 0, stream>>>(fvst, trans, bp);
    backtrace_kernel<<<1, 1024, 0, stream>>>(bp, bestb, out);
}

// Round 2
// 19619.344 us; speedup vs baseline: 1.4089x; 1.4089x over previous
//
#include <hip/hip_runtime.h>
#include <hip/hip_bf16.h>
#include <stdint.h>
#include <math.h>

// Problem dims
constexpr int SEQ  = 4096;
constexpr int DIN  = 1152;
constexpr int HID  = 512;
constexpr int G4H  = 2048;   // 4*HID
constexpr int KTAG = 24;
constexpr float NEGV = -10000.0f;

__device__ __forceinline__ float sigm(float x) { return 1.0f / (1.0f + expf(-x)); }

// =====================================================================
// GEMM: C[SEQ][2048] = A[SEQ][KA] @ W[2048][KA]^T + b     (fp32, 64x64 tile)
// mode 0: A is a plain [SEQ][KA] matrix.
// mode 1: A row t is concat(hf[t+1][0:512], hb[SEQ-t][0:512])  (bidir LSTM output)
// blockIdx.z selects the (Wf,bf,Cf) or (Wb,bb,Cb) problem.
// =====================================================================
__global__ __launch_bounds__(256) void gemm_proj(
    const float* __restrict__ A, const float* __restrict__ hf, const float* __restrict__ hb,
    int KA, int mode,
    const float* __restrict__ Wf, const float* __restrict__ bf, float* __restrict__ Cf,
    const float* __restrict__ Wb, const float* __restrict__ bb, float* __restrict__ Cb)
{
    const float* W    = blockIdx.z ? Wb : Wf;
    const float* bias = blockIdx.z ? bb : bf;
    float*       C    = blockIdx.z ? Cb : Cf;

    __shared__ __align__(16) float As[32][68];   // [k][m], pad 68 to break conflicts, keep 16B align
    __shared__ __align__(16) float Ws[32][68];   // [k][n]

    const int tid  = threadIdx.x;
    const int bm   = blockIdx.x * 64;
    const int bn   = blockIdx.y * 64;
    const int lrow = tid >> 2;          // 0..63
    const int kq   = (tid & 3) * 8;     // 0,8,16,24
    const int tx   = tid & 15, ty = tid >> 4;

    float acc[4][4] = {};

    for (int bk = 0; bk < KA; bk += 32) {
        float4 a0, a1;
        const int arow = bm + lrow;
        const int k0   = bk + kq;
        if (mode == 0) {
            const float* p = A + (size_t)arow * KA + k0;
            a0 = *(const float4*)p;
            a1 = *(const float4*)(p + 4);
        } else {
            const float* p0 = (k0 < 512) ? (hf + (size_t)(arow + 1) * HID + k0)
                                         : (hb + (size_t)(SEQ - arow) * HID + (k0 - 512));
            const int k1 = k0 + 4;
            const float* p1 = (k1 < 512) ? (hf + (size_t)(arow + 1) * HID + k1)
                                         : (hb + (size_t)(SEQ - arow) * HID + (k1 - 512));
            a0 = *(const float4*)p0;
            a1 = *(const float4*)p1;
        }
        const float* q = W + (size_t)(bn + lrow) * KA + k0;
        const float4 w0 = *(const float4*)q;
        const float4 w1 = *(const float4*)(q + 4);

        As[kq+0][lrow] = a0.x; As[kq+1][lrow] = a0.y; As[kq+2][lrow] = a0.z; As[kq+3][lrow] = a0.w;
        As[kq+4][lrow] = a1.x; As[kq+5][lrow] = a1.y; As[kq+6][lrow] = a1.z; As[kq+7][lrow] = a1.w;
        Ws[kq+0][lrow] = w0.x; Ws[kq+1][lrow] = w0.y; Ws[kq+2][lrow] = w0.z; Ws[kq+3][lrow] = w0.w;
        Ws[kq+4][lrow] = w1.x; Ws[kq+5][lrow] = w1.y; Ws[kq+6][lrow] = w1.z; Ws[kq+7][lrow] = w1.w;
        __syncthreads();

        #pragma unroll
        for (int kk = 0; kk < 32; ++kk) {
            const float4 av = *(const float4*)&As[kk][ty * 4];
            const float4 wv = *(const float4*)&Ws[kk][tx * 4];
            acc[0][0] = fmaf(av.x, wv.x, acc[0][0]); acc[0][1] = fmaf(av.x, wv.y, acc[0][1]);
            acc[0][2] = fmaf(av.x, wv.z, acc[0][2]); acc[0][3] = fmaf(av.x, wv.w, acc[0][3]);
            acc[1][0] = fmaf(av.y, wv.x, acc[1][0]); acc[1][1] = fmaf(av.y, wv.y, acc[1][1]);
            acc[1][2] = fmaf(av.y, wv.z, acc[1][2]); acc[1][3] = fmaf(av.y, wv.w, acc[1][3]);
            acc[2][0] = fmaf(av.z, wv.x, acc[2][0]); acc[2][1] = fmaf(av.z, wv.y, acc[2][1]);
            acc[2][2] = fmaf(av.z, wv.z, acc[2][2]); acc[2][3] = fmaf(av.z, wv.w, acc[2][3]);
            acc[3][0] = fmaf(av.w, wv.x, acc[3][0]); acc[3][1] = fmaf(av.w, wv.y, acc[3][1]);
            acc[3][2] = fmaf(av.w, wv.z, acc[3][2]); acc[3][3] = fmaf(av.w, wv.w, acc[3][3]);
        }
        __syncthreads();
    }

    const float4 bv = *(const float4*)&bias[bn + tx * 4];
    #pragma unroll
    for (int im = 0; im < 4; ++im) {
        float4 o;
        o.x = acc[im][0] + bv.x; o.y = acc[im][1] + bv.y;
        o.z = acc[im][2] + bv.z; o.w = acc[im][3] + bv.w;
        *(float4*)&C[(size_t)(bm + ty * 4 + im) * G4H + bn + tx * 4] = o;
    }
}

// =====================================================================
// Persistent bidirectional LSTM layer, v3.
// Structure = v1 (LDS part[] cross-wave reduce, wave0 single batched
// 8x4B contiguous hist store -> ONE write transaction per WG per step;
// v2's 4-wave fragmented stores quadrupled WRITE_SIZE and delayed
// consumer visibility). Plus the three v2 elements that were sound:
//   - zP (input-projection term) prefetched ONE STEP AHEAD: its ~LLC
//     latency sat on wave0's critical path in v1 (issued and consumed
//     within the same step, only ~350cy of cover).
//   - 2 barriers/step instead of 3: the pre-spin barrier was redundant
//     (all hs reads complete before B1; part[] reuse is protected by B2).
//   - single 64-bit poll load instead of two 32-bit.
// 128 WGs x 256 threads. WGs [0,64): forward, [64,128): backward.
// Each WG owns 8 hidden units (32 z-rows). Whh rows in VGPRs.
// h exchanged via hist[s] slots in global memory using NaN-sentinel
// value-spin (relaxed agent-scope atomics). hist pre-filled 0xFF.
// =====================================================================
__global__ __launch_bounds__(256) void lstm_layer(
    const float* __restrict__ Pf, const float* __restrict__ Pb,
    const float* __restrict__ Whhf, const float* __restrict__ Whhb,
    const float* __restrict__ h0, const float* __restrict__ c0, int h0base,
    float* __restrict__ histf, float* __restrict__ histb)
{
    const int wg  = blockIdx.x;
    const int dir = wg >> 6;            // 0 fwd, 1 bwd
    const int w   = wg & 63;            // slice id
    const float* P    = dir ? Pb : Pf;
    const float* Whh  = dir ? Whhb : Whhf;
    float* histW      = dir ? histb : histf;

    const int tid  = threadIdx.x;
    const int wave = tid >> 6;
    const int lane = tid & 63;
    const int r    = lane & 31;                    // local row 0..31
    const int cc   = (wave << 1) | (lane >> 5);    // k-chunk 0..7 (64 wide)
    const int gate = r >> 3;
    const int jj8  = (w << 3) | (r & 7);           // hidden index in [0,512)
    const int grow = gate * HID + jj8;             // z row in [0,2048)

    // weights -> registers (64 floats)
    float4 wv[16];
    {
        const float4* wp = (const float4*)(Whh + (size_t)grow * HID + cc * 64);
        #pragma unroll
        for (int i = 0; i < 16; ++i) wv[i] = wp[i];
    }

    // cell state (wave 0, lanes 0..7)
    float c = 0.0f;
    if (wave == 0 && lane < 8) c = c0[(size_t)(h0base + dir) * HID + (w << 3) + lane];

    __shared__ __align__(16) float hs[512];
    __shared__ float part[4][32];

    // initial h
    {
        const float2 h2 = *(const float2*)&h0[(size_t)(h0base + dir) * HID + tid * 2];
        *(float2*)&hs[tid * 2] = h2;
    }
    __syncthreads();

    // zP for step 0; thereafter software-pipelined one step ahead so the
    // LLC-latency load is issued a full step (~5000cy) before its use.
    float zPc = 0.0f;
    if (wave == 0) zPc = P[(size_t)(dir ? (SEQ - 1) : 0) * G4H + grow];

    for (int s = 0; s < SEQ; ++s) {
        // prefetch NEXT step's input-projection term (off critical path)
        float zPn = 0.0f;
        if (wave == 0 && s + 1 < SEQ) {
            const int tn = dir ? (SEQ - 2 - s) : (s + 1);
            zPn = P[(size_t)tn * G4H + grow];
        }

        // matvec partial: rows for this lane, k in [cc*64, cc*64+64)
        // (same 64-fma dependent chain, same order -> bit-exact)
        float acc = 0.0f;
        const float* hbase = &hs[cc * 64];
        #pragma unroll
        for (int i = 0; i < 16; ++i) {
            const float4 h4 = *(const float4*)&hbase[i * 4];
            acc = fmaf(wv[i].x, h4.x, acc);
            acc = fmaf(wv[i].y, h4.y, acc);
            acc = fmaf(wv[i].z, h4.z, acc);
            acc = fmaf(wv[i].w, h4.w, acc);
        }
        acc += __shfl_xor(acc, 32);                // combine the 2 k-chunks of this wave
        if (lane < 32) part[wave][r] = acc;
        __syncthreads();                           // B1: part ready, hs reads done

        if (wave == 0) {
            float z = part[0][r] + part[1][r] + part[2][r] + part[3][r] + zPc;
            const int jl = lane & 7;
            const float zi = __shfl(z, jl);
            const float zf = __shfl(z, jl + 8);
            const float zg = __shfl(z, jl + 16);
            const float zo = __shfl(z, jl + 24);
            const float cn = sigm(zf) * c + sigm(zi) * tanhf(zg);
            const float hv = sigm(zo) * tanhf(cn);
            if (lane < 8) {
                c = cn;
                // 8 lanes x 4B contiguous = one 32B write transaction
                __hip_atomic_store(&histW[(size_t)(s + 1) * HID + (w << 3) + lane], hv,
                                   __ATOMIC_RELAXED, __HIP_MEMORY_SCOPE_AGENT);
            }
        }
        zPc = zPn;

        if (s + 1 < SEQ) {
            // NO barrier here: waves 1-3 reach the spin immediately after B1
            // and poll while wave0 finishes its tail. hs writes below race
            // nothing (all hs reads completed before B1); part[] reuse next
            // iteration is ordered by B2 (wave0 passes B2 only after its
            // part reads).
            const uint64_t* src = (const uint64_t*)(histW + (size_t)(s + 1) * HID);
            uint64_t v;
            do {
                v = __hip_atomic_load(&src[tid], __ATOMIC_RELAXED, __HIP_MEMORY_SCOPE_AGENT);
            } while ((uint32_t)v == 0xFFFFFFFFu || (uint32_t)(v >> 32) == 0xFFFFFFFFu);
            float2 h2;
            h2.x = __uint_as_float((uint32_t)v);
            h2.y = __uint_as_float((uint32_t)(v >> 32));
            *(float2*)&hs[tid * 2] = h2;
            __syncthreads();                       // B2: hs[s+1] complete
        }
    }
}

// =====================================================================
// feats[t][j] = b_tag[j] + sum_k y1[t][k] * Wtag[j][k], y1 from hist buffers.
// One wave per t-row.
// =====================================================================
__global__ __launch_bounds__(256) void feats_kernel(
    const float* __restrict__ hf, const float* __restrict__ hb,
    const float* __restrict__ Wtag, const float* __restrict__ btag, float* __restrict__ feats)
{
    const int wv = threadIdx.x >> 6, lane = threadIdx.x & 63;
    const int t  = blockIdx.x * 4 + wv;
    const int k0 = lane * 16;
    const float* src = (k0 < 512) ? (hf + (size_t)(t + 1) * HID + k0)
                                  : (hb + (size_t)(SEQ - t) * HID + (k0 - 512));
    const float4 y0 = ((const float4*)src)[0];
    const float4 y1 = ((const float4*)src)[1];
    const float4 y2 = ((const float4*)src)[2];
    const float4 y3 = ((const float4*)src)[3];
    for (int j = 0; j < KTAG; ++j) {
        const float4* wp = (const float4*)&Wtag[(size_t)j * 1024 + k0];
        const float4 w0 = wp[0], w1 = wp[1], w2 = wp[2], w3 = wp[3];
        float p = 0.0f;
        p = fmaf(y0.x, w0.x, p); p = fmaf(y0.y, w0.y, p); p = fmaf(y0.z, w0.z, p); p = fmaf(y0.w, w0.w, p);
        p = fmaf(y1.x, w1.x, p); p = fmaf(y1.y, w1.y, p); p = fmaf(y1.z, w1.z, p); p = fmaf(y1.w, w1.w, p);
        p = fmaf(y2.x, w2.x, p); p = fmaf(y2.y, w2.y, p); p = fmaf(y2.z, w2.z, p); p = fmaf(y2.w, w2.w, p);
        p = fmaf(y3.x, w3.x, p); p = fmaf(y3.y, w3.y, p); p = fmaf(y3.z, w3.z, p); p = fmaf(y3.w, w3.w, p);
        #pragma unroll
        for (int off = 32; off; off >>= 1) p += __shfl_xor(p, off);
        if (lane == 0) feats[(size_t)t * KTAG + j] = p + btag[j];
    }
}

// =====================================================================
// Sequential Viterbi max scan (bit-exact vs reference, no argmax on chain).
// 1 wave. Lane layout: to = lane%24, half = lane/24 covers 12 'from' each.
// fv rows stored to fvstore (slot 0 = init, slot t+1 = fv_t) for bp recompute.
// =====================================================================
__global__ __launch_bounds__(64) void viterbi_scan(
    const float* __restrict__ feats, const float* __restrict__ trans,
    float* __restrict__ fvstore, float* __restrict__ out, int* __restrict__ bestb)
{
    const int lane = threadIdx.x;
    const int to = lane % 24, hh = lane / 24;
    const bool act = hh < 2;
    const int hb = (hh & 1) * 12;

    float tr[12], fvr[12];
    #pragma unroll
    for (int i = 0; i < 12; ++i) tr[i] = act ? trans[to * 24 + hb + i] : -3.0e37f;
    #pragma unroll
    for (int i = 0; i < 12; ++i) fvr[i] = (hb + i == 0) ? 0.0f : NEGV;
    if (lane < 24) fvstore[lane] = (lane == 0) ? 0.0f : NEGV;

    float ftc = (lane < 24) ? feats[lane] : 0.0f;
    const int partner = act ? (to + ((hh ^ 1) * 24)) : lane;
    float fvnew = 0.0f;

    for (int t = 0; t < SEQ; ++t) {
        const float ftn = (lane < 24 && t + 1 < SEQ) ? feats[(size_t)(t + 1) * KTAG + lane] : 0.0f;
        float v0  = fvr[0]  + tr[0],  v1  = fvr[1]  + tr[1];
        float v2  = fvr[2]  + tr[2],  v3  = fvr[3]  + tr[3];
        float v4  = fvr[4]  + tr[4],  v5  = fvr[5]  + tr[5];
        float v6  = fvr[6]  + tr[6],  v7  = fvr[7]  + tr[7];
        float v8  = fvr[8]  + tr[8],  v9  = fvr[9]  + tr[9];
        float v10 = fvr[10] + tr[10], v11 = fvr[11] + tr[11];
        float m = fmaxf(fmaxf(fmaxf(v0, v1), fmaxf(v2, v3)),
                        fmaxf(fmaxf(v4, v5), fmaxf(v6, v7)));
        m = fmaxf(m, fmaxf(fmaxf(v8, v9), fmaxf(v10, v11)));
        m = fmaxf(m, __shfl(m, partner));
        fvnew = m + ftc;                 // valid on lanes < 24
        if (lane < 24) fvstore[(size_t)(t + 1) * KTAG + lane] = fvnew;
        #pragma unroll
        for (int i = 0; i < 12; ++i) fvr[i] = __shfl(fvnew, hb + i);   // re-replicate
        ftc = ftn;
    }

    // terminal
    float val = -3.0e38f; int idx = lane;
    if (lane < 24) {
        val = fvnew + trans[1 * 24 + lane];          // transitions[STOP][from]
        if (lane == 0 || lane == 1) val = NEGV;      // exclude START, STOP
    }
    #pragma unroll
    for (int off = 16; off; off >>= 1) {
        const float ov = __shfl_xor(val, off);
        const int   oi = __shfl_xor(idx, off);
        if (ov > val || (ov == val && oi < idx)) { val = ov; idx = oi; }
    }
    if (lane == 0) { out[0] = val; *bestb = idx; }
}

// =====================================================================
// Recompute backpointers in parallel: bp[t][to] = argmax_from(fv_{t-1}[from]+trans)
// Identical fp32 adds + first-index tie rule -> matches the sequential scan.
// =====================================================================
__global__ __launch_bounds__(256) void bp_kernel(
    const float* __restrict__ fvstore, const float* __restrict__ trans, uint8_t* __restrict__ bp)
{
    const int idx = blockIdx.x * 256 + threadIdx.x;
    const int t = idx / KTAG, to = idx % KTAG;
    const float* fv = fvstore + (size_t)t * KTAG;   // slot t = fv_{t-1}
    const float* tr = trans + to * 24;
    float m = fv[0] + tr[0]; int bi = 0;
    #pragma unroll
    for (int f = 1; f < 24; ++f) {
        const float v = fv[f] + tr[f];
        if (v > m) { m = v; bi = f; }
    }
    bp[idx] = (uint8_t)bi;
}

// =====================================================================
// Parallel backtrace via exact integer map composition over 64-step chunks.
// =====================================================================
__global__ __launch_bounds__(1024) void backtrace_kernel(
    const uint8_t* __restrict__ bp, const int* __restrict__ bestb, float* __restrict__ out)
{
    __shared__ uint8_t E[64][24];
    __shared__ uint8_t tops[64];
    const int tid = threadIdx.x;
    const int wv = tid >> 6, lane = tid & 63;

    // phase 1: chunk maps E_c: top_c -> top_{c-1} (applies bp[64c+63] .. bp[64c])
    for (int ci = 0; ci < 4; ++ci) {
        const int ck = wv * 4 + ci;
        if (lane < 24) {
            int y = lane;
            for (int k = 63; k >= 0; --k) y = bp[(size_t)(ck * 64 + k) * KTAG + y];
            E[ck][lane] = (uint8_t)y;
        }
    }
    __syncthreads();

    // phase 2: serial fold over 64 chunk maps
    if (tid == 0) {
        int topc = *bestb;
        tops[63] = (uint8_t)topc;
        for (int ck = 63; ck >= 1; --ck) { topc = E[ck][topc]; tops[ck - 1] = (uint8_t)topc; }
    }
    __syncthreads();

    // phase 3: fill each chunk
    for (int ci = 0; ci < 4; ++ci) {
        const int ck = wv * 4 + ci;
        if (lane == 0) {
            int y = tops[ck];
            out[1 + ck * 64 + 63] = (float)y;
            for (int tt = ck * 64 + 62; tt >= ck * 64; --tt) {
                y = bp[(size_t)(tt + 1) * KTAG + y];
                out[1 + tt] = (float)y;
            }
        }
    }
}

// =====================================================================
extern "C" void kernel_launch(void* const* d_in, const int* in_sizes, int n_in,
                              void* d_out, int out_size, void* d_ws, size_t ws_size,
                              hipStream_t stream)
{
    (void)in_sizes; (void)n_in; (void)out_size; (void)ws_size;
    // Inputs in setup_inputs() dict INSERTION order: transitions is added
    // LAST (after h0/c0), even though the reference signature lists it earlier.
    const float* X     = (const float*)d_in[0];
    const float* Wih0f = (const float*)d_in[1];
    const float* Whh0f = (const float*)d_in[2];
    const float* b0f   = (const float*)d_in[3];
    const float* Wih0b = (const float*)d_in[4];
    const float* Whh0b = (const float*)d_in[5];
    const float* b0b   = (const float*)d_in[6];
    const float* Wih1f = (const float*)d_in[7];
    const float* Whh1f = (const float*)d_in[8];
    const float* b1f   = (const float*)d_in[9];
    const float* Wih1b = (const float*)d_in[10];
    const float* Whh1b = (const float*)d_in[11];
    const float* b1b   = (const float*)d_in[12];
    const float* Wtag  = (const float*)d_in[13];
    const float* btag  = (const float*)d_in[14];
    const float* h0    = (const float*)d_in[15];
    const float* c0    = (const float*)d_in[16];
    const float* trans = (const float*)d_in[17];
    float* out = (float*)d_out;

    // workspace carve-up (floats)
    float* f   = (float*)d_ws;
    float* Pf  = f;                                   // SEQ*2048
    float* Pb  = Pf  + (size_t)SEQ * G4H;             // SEQ*2048
    float* hf0 = Pb  + (size_t)SEQ * G4H;             // (SEQ+1)*512 each
    float* hb0 = hf0 + (size_t)(SEQ + 1) * HID;
    float* hf1 = hb0 + (size_t)(SEQ + 1) * HID;
    float* hb1 = hf1 + (size_t)(SEQ + 1) * HID;
    float* feats = hb1 + (size_t)(SEQ + 1) * HID;     // SEQ*24
    float* fvst  = feats + (size_t)SEQ * KTAG;        // (SEQ+1)*24
    int*   bestb = (int*)(fvst + (size_t)(SEQ + 1) * KTAG);
    uint8_t* bp  = (uint8_t*)(bestb + 4);             // SEQ*24 bytes

    // NaN-sentinel fill for all 4 hist buffers (sync mechanism for the LSTM)
    hipMemsetAsync(hf0, 0xFF, (size_t)4 * (SEQ + 1) * HID * sizeof(float), stream);

    // layer 0: input projection, then persistent bidirectional recurrence
    gemm_proj<<<dim3(SEQ / 64, G4H / 64, 2), 256, 0, stream>>>(
        X, nullptr, nullptr, DIN, 0, Wih0f, b0f, Pf, Wih0b, b0b, Pb);
    lstm_layer<<<128, 256, 0, stream>>>(Pf, Pb, Whh0f, Whh0b, h0, c0, 0, hf0, hb0);

    // layer 1 (P buffers reused; layer-0 input y0 read straight from hist)
    gemm_proj<<<dim3(SEQ / 64, G4H / 64, 2), 256, 0, stream>>>(
        nullptr, hf0, hb0, 1024, 1, Wih1f, b1f, Pf, Wih1b, b1b, Pb);
    lstm_layer<<<128, 256, 0, stream>>>(Pf, Pb, Whh1f, Whh1b, h0, c0, 2, hf1, hb1);

    // tag head + Viterbi
    feats_kernel<<<SEQ / 4, 256, 0, stream>>>(hf1, hb1, Wtag, btag, feats);
    viterbi_scan<<<1, 64, 0, stream>>>(feats, trans, fvst, out, bestb);
    bp_kernel<<<(SEQ * KTAG) / 256, 256, 0, stream>>>(fvst, trans, bp);
    backtrace_kernel<<<1, 1024, 0, stream>>>(bp, bestb, out);
}

// Round 3
// 17324.738 us; speedup vs baseline: 1.5956x; 1.1324x over previous
//
#include <hip/hip_runtime.h>
#include <hip/hip_bf16.h>
#include <stdint.h>
#include <math.h>

// Problem dims
constexpr int SEQ  = 4096;
constexpr int DIN  = 1152;
constexpr int HID  = 512;
constexpr int G4H  = 2048;   // 4*HID
constexpr int KTAG = 24;
constexpr float NEGV = -10000.0f;

__device__ __forceinline__ float sigm(float x) { return 1.0f / (1.0f + expf(-x)); }

// =====================================================================
// GEMM: C[SEQ][2048] = A[SEQ][KA] @ W[2048][KA]^T + b     (fp32, 64x64 tile)
// mode 0: A is a plain [SEQ][KA] matrix.
// mode 1: A row t is concat(hf[t+1][0:512], hb[SEQ-t][0:512])  (bidir LSTM output)
// blockIdx.z selects the (Wf,bf,Cf) or (Wb,bb,Cb) problem.
// =====================================================================
__global__ __launch_bounds__(256) void gemm_proj(
    const float* __restrict__ A, const float* __restrict__ hf, const float* __restrict__ hb,
    int KA, int mode,
    const float* __restrict__ Wf, const float* __restrict__ bf, float* __restrict__ Cf,
    const float* __restrict__ Wb, const float* __restrict__ bb, float* __restrict__ Cb)
{
    const float* W    = blockIdx.z ? Wb : Wf;
    const float* bias = blockIdx.z ? bb : bf;
    float*       C    = blockIdx.z ? Cb : Cf;

    __shared__ __align__(16) float As[32][68];   // [k][m], pad 68 to break conflicts, keep 16B align
    __shared__ __align__(16) float Ws[32][68];   // [k][n]

    const int tid  = threadIdx.x;
    const int bm   = blockIdx.x * 64;
    const int bn   = blockIdx.y * 64;
    const int lrow = tid >> 2;          // 0..63
    const int kq   = (tid & 3) * 8;     // 0,8,16,24
    const int tx   = tid & 15, ty = tid >> 4;

    float acc[4][4] = {};

    for (int bk = 0; bk < KA; bk += 32) {
        float4 a0, a1;
        const int arow = bm + lrow;
        const int k0   = bk + kq;
        if (mode == 0) {
            const float* p = A + (size_t)arow * KA + k0;
            a0 = *(const float4*)p;
            a1 = *(const float4*)(p + 4);
        } else {
            const float* p0 = (k0 < 512) ? (hf + (size_t)(arow + 1) * HID + k0)
                                         : (hb + (size_t)(SEQ - arow) * HID + (k0 - 512));
            const int k1 = k0 + 4;
            const float* p1 = (k1 < 512) ? (hf + (size_t)(arow + 1) * HID + k1)
                                         : (hb + (size_t)(SEQ - arow) * HID + (k1 - 512));
            a0 = *(const float4*)p0;
            a1 = *(const float4*)p1;
        }
        const float* q = W + (size_t)(bn + lrow) * KA + k0;
        const float4 w0 = *(const float4*)q;
        const float4 w1 = *(const float4*)(q + 4);

        As[kq+0][lrow] = a0.x; As[kq+1][lrow] = a0.y; As[kq+2][lrow] = a0.z; As[kq+3][lrow] = a0.w;
        As[kq+4][lrow] = a1.x; As[kq+5][lrow] = a1.y; As[kq+6][lrow] = a1.z; As[kq+7][lrow] = a1.w;
        Ws[kq+0][lrow] = w0.x; Ws[kq+1][lrow] = w0.y; Ws[kq+2][lrow] = w0.z; Ws[kq+3][lrow] = w0.w;
        Ws[kq+4][lrow] = w1.x; Ws[kq+5][lrow] = w1.y; Ws[kq+6][lrow] = w1.z; Ws[kq+7][lrow] = w1.w;
        __syncthreads();

        #pragma unroll
        for (int kk = 0; kk < 32; ++kk) {
            const float4 av = *(const float4*)&As[kk][ty * 4];
            const float4 wv = *(const float4*)&Ws[kk][tx * 4];
            acc[0][0] = fmaf(av.x, wv.x, acc[0][0]); acc[0][1] = fmaf(av.x, wv.y, acc[0][1]);
            acc[0][2] = fmaf(av.x, wv.z, acc[0][2]); acc[0][3] = fmaf(av.x, wv.w, acc[0][3]);
            acc[1][0] = fmaf(av.y, wv.x, acc[1][0]); acc[1][1] = fmaf(av.y, wv.y, acc[1][1]);
            acc[1][2] = fmaf(av.y, wv.z, acc[1][2]); acc[1][3] = fmaf(av.y, wv.w, acc[1][3]);
            acc[2][0] = fmaf(av.z, wv.x, acc[2][0]); acc[2][1] = fmaf(av.z, wv.y, acc[2][1]);
            acc[2][2] = fmaf(av.z, wv.z, acc[2][2]); acc[2][3] = fmaf(av.z, wv.w, acc[2][3]);
            acc[3][0] = fmaf(av.w, wv.x, acc[3][0]); acc[3][1] = fmaf(av.w, wv.y, acc[3][1]);
            acc[3][2] = fmaf(av.w, wv.z, acc[3][2]); acc[3][3] = fmaf(av.w, wv.w, acc[3][3]);
        }
        __syncthreads();
    }

    const float4 bv = *(const float4*)&bias[bn + tx * 4];
    #pragma unroll
    for (int im = 0; im < 4; ++im) {
        float4 o;
        o.x = acc[im][0] + bv.x; o.y = acc[im][1] + bv.y;
        o.z = acc[im][2] + bv.z; o.w = acc[im][3] + bv.w;
        *(float4*)&C[(size_t)(bm + ty * 4 + im) * G4H + bn + tx * 4] = o;
    }
}

// =====================================================================
// Persistent bidirectional LSTM layer, v4: halve the sync fan-in.
// 64 WGs x 512 threads. WGs [0,32): forward, [32,64): backward.
// Each WG owns 16 hidden units = 64 z-rows. Thread = (row, chunk):
//   wave W in [0,8): gate g = W>>1, unit-sub usub = (W&1)*8
//   lane = q*8 + rr:  q = 64-float k-chunk 0..7, rr = row-in-wave 0..7
//   unit = w*16 + usub + rr,  grow = g*512 + unit.
// Per-lane matvec = the SAME ordered 64-fma chain over k in [64q,64q+64).
// Combine reproduces v1's association exactly:
//   s2_i = c_{2i}+c_{2i+1} (shfl_xor 8, even-q lanes have even+odd order)
//   z = ((s2_0+s2_1)+s2_2)+s2_3 + zP      -> bit-exact, absmax must stay 0.
// Gates cross waves once through LDS zb[4][16]; 16 lanes do the cell
// update and ONE 64B contiguous hist store per WG (was 2x32B).
// Rationale (from v3 null result + VGPR=56):
//   - per-step period = lockstep RT + max-over-producers jitter; producers
//     per direction 64 -> 32 shrinks the max; sync events halve.
//   - named float4 w0..w15 + __launch_bounds__(512,2) to keep weights
//     VGPR-resident (v3 compiled to 56 VGPR = weights re-loaded per step).
//   - 8 waves/WG gives 2x TLP per SIMD to hide residual L2 traffic.
//   - zP still software-pipelined one step ahead; 2 barriers/step;
//     padded LDS h (68-float chunk stride) -> conflict-free broadcast reads.
// h exchanged via hist[s] slots, NaN-sentinel value-spin (relaxed agent
// atomics); hist pre-filled 0xFF.
// =====================================================================
__global__ __launch_bounds__(512, 2) void lstm_layer(
    const float* __restrict__ Pf, const float* __restrict__ Pb,
    const float* __restrict__ Whhf, const float* __restrict__ Whhb,
    const float* __restrict__ h0, const float* __restrict__ c0, int h0base,
    float* __restrict__ histf, float* __restrict__ histb)
{
    const int wg  = blockIdx.x;
    const int dir = wg >> 5;            // 0 fwd, 1 bwd (32 WGs each)
    const int w   = wg & 31;            // slice id: units [w*16, w*16+16)
    const float* P    = dir ? Pb : Pf;
    const float* Whh  = dir ? Whhb : Whhf;
    float* histW      = dir ? histb : histf;

    const int tid  = threadIdx.x;              // 0..511
    const int wave = tid >> 6;                 // 0..7
    const int lane = tid & 63;
    const int q    = lane >> 3;                // k-chunk 0..7
    const int rr   = lane & 7;                 // row-in-wave 0..7
    const int g    = wave >> 1;                // gate 0..3 (i,f,g,o)
    const int usub = (wave & 1) * 8;
    const int uu   = usub + rr;                // unit-in-WG 0..15 (this row)
    const int unit = w * 16 + uu;              // global unit [0,512)
    const int grow = g * HID + unit;           // z-row [0,2048)

    // weights -> named registers (64 floats; named to force residency)
    const float4* wp = (const float4*)(Whh + (size_t)grow * HID + q * 64);
    const float4 w0 = wp[0],  w1 = wp[1],  w2 = wp[2],  w3 = wp[3];
    const float4 w4 = wp[4],  w5 = wp[5],  w6 = wp[6],  w7 = wp[7];
    const float4 w8 = wp[8],  w9 = wp[9],  wA = wp[10], wB = wp[11];
    const float4 wC = wp[12], wD = wp[13], wE = wp[14], wF = wp[15];

    // cell state on the first 16 threads (one per unit)
    float c = 0.0f;
    if (tid < 16) c = c0[(size_t)(h0base + dir) * HID + w * 16 + tid];

    // padded h: chunk k lives at [k*68, k*68+64); word (68k+4i) -> bank
    // 4(k+i)%32: the 8 chunk-groups of a wave hit 8 distinct banks per
    // ds_read_b128 (8-lane broadcast within each group) -> conflict-free.
    __shared__ __align__(16) float hsp[8 * 68];
    __shared__ float zb[4][16];

    // initial h into padded LDS
    hsp[(tid >> 6) * 68 + (tid & 63)] = h0[(size_t)(h0base + dir) * HID + tid];
    __syncthreads();

    // zP for step 0; thereafter software-pipelined one step ahead (q==0 lanes)
    float zPc = 0.0f;
    if (q == 0) zPc = P[(size_t)(dir ? (SEQ - 1) : 0) * G4H + grow];

    for (int s = 0; s < SEQ; ++s) {
        // prefetch NEXT step's input-projection term (off critical path)
        float zPn = 0.0f;
        if (q == 0 && s + 1 < SEQ) {
            const int tn = dir ? (SEQ - 2 - s) : (s + 1);
            zPn = P[(size_t)tn * G4H + grow];
        }

        // matvec partial: this lane's ordered 64-fma chain, k in [64q,64q+64)
        float acc = 0.0f;
        {
            const float* hb4 = &hsp[q * 68];
            float4 h4;
            h4 = *(const float4*)&hb4[ 0]; acc = fmaf(w0.x,h4.x,acc); acc = fmaf(w0.y,h4.y,acc); acc = fmaf(w0.z,h4.z,acc); acc = fmaf(w0.w,h4.w,acc);
            h4 = *(const float4*)&hb4[ 4]; acc = fmaf(w1.x,h4.x,acc); acc = fmaf(w1.y,h4.y,acc); acc = fmaf(w1.z,h4.z,acc); acc = fmaf(w1.w,h4.w,acc);
            h4 = *(const float4*)&hb4[ 8]; acc = fmaf(w2.x,h4.x,acc); acc = fmaf(w2.y,h4.y,acc); acc = fmaf(w2.z,h4.z,acc); acc = fmaf(w2.w,h4.w,acc);
            h4 = *(const float4*)&hb4[12]; acc = fmaf(w3.x,h4.x,acc); acc = fmaf(w3.y,h4.y,acc); acc = fmaf(w3.z,h4.z,acc); acc = fmaf(w3.w,h4.w,acc);
            h4 = *(const float4*)&hb4[16]; acc = fmaf(w4.x,h4.x,acc); acc = fmaf(w4.y,h4.y,acc); acc = fmaf(w4.z,h4.z,acc); acc = fmaf(w4.w,h4.w,acc);
            h4 = *(const float4*)&hb4[20]; acc = fmaf(w5.x,h4.x,acc); acc = fmaf(w5.y,h4.y,acc); acc = fmaf(w5.z,h4.z,acc); acc = fmaf(w5.w,h4.w,acc);
            h4 = *(const float4*)&hb4[24]; acc = fmaf(w6.x,h4.x,acc); acc = fmaf(w6.y,h4.y,acc); acc = fmaf(w6.z,h4.z,acc); acc = fmaf(w6.w,h4.w,acc);
            h4 = *(const float4*)&hb4[28]; acc = fmaf(w7.x,h4.x,acc); acc = fmaf(w7.y,h4.y,acc); acc = fmaf(w7.z,h4.z,acc); acc = fmaf(w7.w,h4.w,acc);
            h4 = *(const float4*)&hb4[32]; acc = fmaf(w8.x,h4.x,acc); acc = fmaf(w8.y,h4.y,acc); acc = fmaf(w8.z,h4.z,acc); acc = fmaf(w8.w,h4.w,acc);
            h4 = *(const float4*)&hb4[36]; acc = fmaf(w9.x,h4.x,acc); acc = fmaf(w9.y,h4.y,acc); acc = fmaf(w9.z,h4.z,acc); acc = fmaf(w9.w,h4.w,acc);
            h4 = *(const float4*)&hb4[40]; acc = fmaf(wA.x,h4.x,acc); acc = fmaf(wA.y,h4.y,acc); acc = fmaf(wA.z,h4.z,acc); acc = fmaf(wA.w,h4.w,acc);
            h4 = *(const float4*)&hb4[44]; acc = fmaf(wB.x,h4.x,acc); acc = fmaf(wB.y,h4.y,acc); acc = fmaf(wB.z,h4.z,acc); acc = fmaf(wB.w,h4.w,acc);
            h4 = *(const float4*)&hb4[48]; acc = fmaf(wC.x,h4.x,acc); acc = fmaf(wC.y,h4.y,acc); acc = fmaf(wC.z,h4.z,acc); acc = fmaf(wC.w,h4.w,acc);
            h4 = *(const float4*)&hb4[52]; acc = fmaf(wD.x,h4.x,acc); acc = fmaf(wD.y,h4.y,acc); acc = fmaf(wD.z,h4.z,acc); acc = fmaf(wD.w,h4.w,acc);
            h4 = *(const float4*)&hb4[56]; acc = fmaf(wE.x,h4.x,acc); acc = fmaf(wE.y,h4.y,acc); acc = fmaf(wE.z,h4.z,acc); acc = fmaf(wE.w,h4.w,acc);
            h4 = *(const float4*)&hb4[60]; acc = fmaf(wF.x,h4.x,acc); acc = fmaf(wF.y,h4.y,acc); acc = fmaf(wF.z,h4.z,acc); acc = fmaf(wF.w,h4.w,acc);
        }

        // s2_i = c_{2i} + c_{2i+1}: even-q lanes hold own(even) + partner(odd)
        const float s2 = acc + __shfl_xor(acc, 8);
        // z = ((s2_0 + s2_1) + s2_2) + s2_3 + zP   (exact v1 association);
        // s2_i is valid on lanes 16*i + rr (q = 2i, even).
        float z = __shfl(s2, rr) + __shfl(s2, 16 + rr);
        z += __shfl(s2, 32 + rr);
        z += __shfl(s2, 48 + rr);
        z += __shfl(zPc, rr + (lane & 56) * 0 + (wave << 6 & 0)) * 0.0f +  // (no-op keeper, see below)
             ((q == 0) ? zPc : __shfl(zPc, rr));   // zP lives on q==0 lanes; broadcast within wave

        // write this row's z once (q==0 lanes), gate combine via LDS
        if (q == 0) zb[g][uu] = z;
        __syncthreads();                           // B1: zb ready, hsp reads done

        if (tid < 16) {
            const float zi = zb[0][tid];
            const float zf = zb[1][tid];
            const float zg = zb[2][tid];
            const float zo = zb[3][tid];
            const float cn = sigm(zf) * c + sigm(zi) * tanhf(zg);
            const float hv = sigm(zo) * tanhf(cn);
            c = cn;
            // 16 lanes x 4B contiguous, 64B-aligned = one write transaction
            __hip_atomic_store(&histW[(size_t)(s + 1) * HID + w * 16 + tid], hv,
                               __ATOMIC_RELAXED, __HIP_MEMORY_SCOPE_AGENT);
        }
        zPc = zPn;

        if (s + 1 < SEQ) {
            // waves with tid>=16 arrive here straight from B1 and poll while
            // the cell-update lanes finish their tail.
            const uint32_t* src = (const uint32_t*)(histW + (size_t)(s + 1) * HID);
            uint32_t v;
            do {
                v = __hip_atomic_load(&src[tid], __ATOMIC_RELAXED, __HIP_MEMORY_SCOPE_AGENT);
            } while (v == 0xFFFFFFFFu);
            hsp[(tid >> 6) * 68 + (tid & 63)] = __uint_as_float(v);
            __syncthreads();                       // B2: hs[s+1] complete
        }
    }
}

// =====================================================================
// feats[t][j] = b_tag[j] + sum_k y1[t][k] * Wtag[j][k], y1 from hist buffers.
// One wave per t-row.
// =====================================================================
__global__ __launch_bounds__(256) void feats_kernel(
    const float* __restrict__ hf, const float* __restrict__ hb,
    const float* __restrict__ Wtag, const float* __restrict__ btag, float* __restrict__ feats)
{
    const int wv = threadIdx.x >> 6, lane = threadIdx.x & 63;
    const int t  = blockIdx.x * 4 + wv;
    const int k0 = lane * 16;
    const float* src = (k0 < 512) ? (hf + (size_t)(t + 1) * HID + k0)
                                  : (hb + (size_t)(SEQ - t) * HID + (k0 - 512));
    const float4 y0 = ((const float4*)src)[0];
    const float4 y1 = ((const float4*)src)[1];
    const float4 y2 = ((const float4*)src)[2];
    const float4 y3 = ((const float4*)src)[3];
    for (int j = 0; j < KTAG; ++j) {
        const float4* wp = (const float4*)&Wtag[(size_t)j * 1024 + k0];
        const float4 w0 = wp[0], w1 = wp[1], w2 = wp[2], w3 = wp[3];
        float p = 0.0f;
        p = fmaf(y0.x, w0.x, p); p = fmaf(y0.y, w0.y, p); p = fmaf(y0.z, w0.z, p); p = fmaf(y0.w, w0.w, p);
        p = fmaf(y1.x, w1.x, p); p = fmaf(y1.y, w1.y, p); p = fmaf(y1.z, w1.z, p); p = fmaf(y1.w, w1.w, p);
        p = fmaf(y2.x, w2.x, p); p = fmaf(y2.y, w2.y, p); p = fmaf(y2.z, w2.z, p); p = fmaf(y2.w, w2.w, p);
        p = fmaf(y3.x, w3.x, p); p = fmaf(y3.y, w3.y, p); p = fmaf(y3.z, w3.z, p); p = fmaf(y3.w, w3.w, p);
        #pragma unroll
        for (int off = 32; off; off >>= 1) p += __shfl_xor(p, off);
        if (lane == 0) feats[(size_t)t * KTAG + j] = p + btag[j];
    }
}

// =====================================================================
// Sequential Viterbi max scan (bit-exact vs reference, no argmax on chain).
// 1 wave. Lane layout: to = lane%24, half = lane/24 covers 12 'from' each.
// fv rows stored to fvstore (slot 0 = init, slot t+1 = fv_t) for bp recompute.
// =====================================================================
__global__ __launch_bounds__(64) void viterbi_scan(
    const float* __restrict__ feats, const float* __restrict__ trans,
    float* __restrict__ fvstore, float* __restrict__ out, int* __restrict__ bestb)
{
    const int lane = threadIdx.x;
    const int to = lane % 24, hh = lane / 24;
    const bool act = hh < 2;
    const int hb = (hh & 1) * 12;

    float tr[12], fvr[12];
    #pragma unroll
    for (int i = 0; i < 12; ++i) tr[i] = act ? trans[to * 24 + hb + i] : -3.0e37f;
    #pragma unroll
    for (int i = 0; i < 12; ++i) fvr[i] = (hb + i == 0) ? 0.0f : NEGV;
    if (lane < 24) fvstore[lane] = (lane == 0) ? 0.0f : NEGV;

    float ftc = (lane < 24) ? feats[lane] : 0.0f;
    const int partner = act ? (to + ((hh ^ 1) * 24)) : lane;
    float fvnew = 0.0f;

    for (int t = 0; t < SEQ; ++t) {
        const float ftn = (lane < 24 && t + 1 < SEQ) ? feats[(size_t)(t + 1) * KTAG + lane] : 0.0f;
        float v0  = fvr[0]  + tr[0],  v1  = fvr[1]  + tr[1];
        float v2  = fvr[2]  + tr[2],  v3  = fvr[3]  + tr[3];
        float v4  = fvr[4]  + tr[4],  v5  = fvr[5]  + tr[5];
        float v6  = fvr[6]  + tr[6],  v7  = fvr[7]  + tr[7];
        float v8  = fvr[8]  + tr[8],  v9  = fvr[9]  + tr[9];
        float v10 = fvr[10] + tr[10], v11 = fvr[11] + tr[11];
        float m = fmaxf(fmaxf(fmaxf(v0, v1), fmaxf(v2, v3)),
                        fmaxf(fmaxf(v4, v5), fmaxf(v6, v7)));
        m = fmaxf(m, fmaxf(fmaxf(v8, v9), fmaxf(v10, v11)));
        m = fmaxf(m, __shfl(m, partner));
        fvnew = m + ftc;                 // valid on lanes < 24
        if (lane < 24) fvstore[(size_t)(t + 1) * KTAG + lane] = fvnew;
        #pragma unroll
        for (int i = 0; i < 12; ++i) fvr[i] = __shfl(fvnew, hb + i);   // re-replicate
        ftc = ftn;
    }

    // terminal
    float val = -3.0e38f; int idx = lane;
    if (lane < 24) {
        val = fvnew + trans[1 * 24 + lane];          // transitions[STOP][from]
        if (lane == 0 || lane == 1) val = NEGV;      // exclude START, STOP
    }
    #pragma unroll
    for (int off = 16; off; off >>= 1) {
        const float ov = __shfl_xor(val, off);
        const int   oi = __shfl_xor(idx, off);
        if (ov > val || (ov == val && oi < idx)) { val = ov; idx = oi; }
    }
    if (lane == 0) { out[0] = val; *bestb = idx; }
}

// =====================================================================
// Recompute backpointers in parallel: bp[t][to] = argmax_from(fv_{t-1}[from]+trans)
// Identical fp32 adds + first-index tie rule -> matches the sequential scan.
// =====================================================================
__global__ __launch_bounds__(256) void bp_kernel(
    const float* __restrict__ fvstore, const float* __restrict__ trans, uint8_t* __restrict__ bp)
{
    const int idx = blockIdx.x * 256 + threadIdx.x;
    const int t = idx / KTAG, to = idx % KTAG;
    const float* fv = fvstore + (size_t)t * KTAG;   // slot t = fv_{t-1}
    const float* tr = trans + to * 24;
    float m = fv[0] + tr[0]; int bi = 0;
    #pragma unroll
    for (int f = 1; f < 24; ++f) {
        const float v = fv[f] + tr[f];
        if (v > m) { m = v; bi = f; }
    }
    bp[idx] = (uint8_t)bi;
}

// =====================================================================
// Parallel backtrace via exact integer map composition over 64-step chunks.
// =====================================================================
__global__ __launch_bounds__(1024) void backtrace_kernel(
    const uint8_t* __restrict__ bp, const int* __restrict__ bestb, float* __restrict__ out)
{
    __shared__ uint8_t E[64][24];
    __shared__ uint8_t tops[64];
    const int tid = threadIdx.x;
    const int wv = tid >> 6, lane = tid & 63;

    // phase 1: chunk maps E_c: top_c -> top_{c-1} (applies bp[64c+63] .. bp[64c])
    for (int ci = 0; ci < 4; ++ci) {
        const int ck = wv * 4 + ci;
        if (lane < 24) {
            int y = lane;
            for (int k = 63; k >= 0; --k) y = bp[(size_t)(ck * 64 + k) * KTAG + y];
            E[ck][lane] = (uint8_t)y;
        }
    }
    __syncthreads();

    // phase 2: serial fold over 64 chunk maps
    if (tid == 0) {
        int topc = *bestb;
        tops[63] = (uint8_t)topc;
        for (int ck = 63; ck >= 1; --ck) { topc = E[ck][topc]; tops[ck - 1] = (uint8_t)topc; }
    }
    __syncthreads();

    // phase 3: fill each chunk
    for (int ci = 0; ci < 4; ++ci) {
        const int ck = wv * 4 + ci;
        if (lane == 0) {
            int y = tops[ck];
            out[1 + ck * 64 + 63] = (float)y;
            for (int tt = ck * 64 + 62; tt >= ck * 64; --tt) {
                y = bp[(size_t)(tt + 1) * KTAG + y];
                out[1 + tt] = (float)y;
            }
        }
    }
}

// =====================================================================
extern "C" void kernel_launch(void* const* d_in, const int* in_sizes, int n_in,
                              void* d_out, int out_size, void* d_ws, size_t ws_size,
                              hipStream_t stream)
{
    (void)in_sizes; (void)n_in; (void)out_size; (void)ws_size;
    // Inputs in setup_inputs() dict INSERTION order: transitions is added
    // LAST (after h0/c0), even though the reference signature lists it earlier.
    const float* X     = (const float*)d_in[0];
    const float* Wih0f = (const float*)d_in[1];
    const float* Whh0f = (const float*)d_in[2];
    const float* b0f   = (const float*)d_in[3];
    const float* Wih0b = (const float*)d_in[4];
    const float* Whh0b = (const float*)d_in[5];
    const float* b0b   = (const float*)d_in[6];
    const float* Wih1f = (const float*)d_in[7];
    const float* Whh1f = (const float*)d_in[8];
    const float* b1f   = (const float*)d_in[9];
    const float* Wih1b = (const float*)d_in[10];
    const float* Whh1b = (const float*)d_in[11];
    const float* b1b   = (const float*)d_in[12];
    const float* Wtag  = (const float*)d_in[13];
    const float* btag  = (const float*)d_in[14];
    const float* h0    = (const float*)d_in[15];
    const float* c0    = (const float*)d_in[16];
    const float* trans = (const float*)d_in[17];
    float* out = (float*)d_out;

    // workspace carve-up (floats)
    float* f   = (float*)d_ws;
    float* Pf  = f;                                   // SEQ*2048
    float* Pb  = Pf  + (size_t)SEQ * G4H;             // SEQ*2048
    float* hf0 = Pb  + (size_t)SEQ * G4H;             // (SEQ+1)*512 each
    float* hb0 = hf0 + (size_t)(SEQ + 1) * HID;
    float* hf1 = hb0 + (size_t)(SEQ + 1) * HID;
    float* hb1 = hf1 + (size_t)(SEQ + 1) * HID;
    float* feats = hb1 + (size_t)(SEQ + 1) * HID;     // SEQ*24
    float* fvst  = feats + (size_t)SEQ * KTAG;        // (SEQ+1)*24
    int*   bestb = (int*)(fvst + (size_t)(SEQ + 1) * KTAG);
    uint8_t* bp  = (uint8_t*)(bestb + 4);             // SEQ*24 bytes

    // NaN-sentinel fill for all 4 hist buffers (sync mechanism for the LSTM)
    hipMemsetAsync(hf0, 0xFF, (size_t)4 * (SEQ + 1) * HID * sizeof(float), stream);

    // layer 0: input projection, then persistent bidirectional recurrence
    gemm_proj<<<dim3(SEQ / 64, G4H / 64, 2), 256, 0, stream>>>(
        X, nullptr, nullptr, DIN, 0, Wih0f, b0f, Pf, Wih0b, b0b, Pb);
    lstm_layer<<<64, 512, 0, stream>>>(Pf, Pb, Whh0f, Whh0b, h0, c0, 0, hf0, hb0);

    // layer 1 (P buffers reused; layer-0 input y0 read straight from hist)
    gemm_proj<<<dim3(SEQ / 64, G4H / 64, 2), 256, 0, stream>>>(
        nullptr, hf0, hb0, 1024, 1, Wih1f, b1f, Pf, Wih1b, b1b, Pb);
    lstm_layer<<<64, 512, 0, stream>>>(Pf, Pb, Whh1f, Whh1b, h0, c0, 2, hf1, hb1);

    // tag head + Viterbi
    feats_kernel<<<SEQ / 4, 256, 0, stream>>>(hf1, hb1, Wtag, btag, feats);
    viterbi_scan<<<1, 64, 0, stream>>>(feats, trans, fvst, out, bestb);
    bp_kernel<<<(SEQ * KTAG) / 256, 256, 0, stream>>>(fvst, trans, bp);
    backtrace_kernel<<<1, 1024, 0, stream>>>(bp, bestb, out);
}